// Round 5
// baseline (258.812 us; speedup 1.0000x reference)
//
#include <hip/hip_runtime.h>

#define NUSR 8192
#define HDIM 256

typedef __attribute__((ext_vector_type(8))) __bf16 bf16x8;
typedef __attribute__((ext_vector_type(4))) float f32x4;

union frag_u { bf16x8 v; unsigned short u[8]; unsigned int d[4]; };

// f32 -> bf16 RNE
__device__ __forceinline__ unsigned int f2bf(float f) {
  unsigned u = __builtin_bit_cast(unsigned, f);
  u += 0x7FFFu + ((u >> 16) & 1u);
  return u >> 16;
}
__device__ __forceinline__ unsigned int f2bf2(float lo, float hi) {
  return f2bf(lo) | (f2bf(hi) << 16);
}
__device__ __forceinline__ float sigmoidf_fast(float x) {
  float e = __builtin_amdgcn_exp2f(x * -1.44269504088896340736f);
  return __builtin_amdgcn_rcpf(1.0f + e);
}

// PX layout (proj in MFMA-B fragment order), ushort offsets:
//   PX[(col>>4)*4096 + (k>>5)*512 + ((k>>3)&3)*128 + (col&15)*8 + (k&7)]
// -> B-frag for (col16 ct, kb) = 16B at PX + ct*4096 + kb*512 + lane*8 (lane-linear).

// ---------------------------------------------------------------------------
// k1_fused: ONE launch doing both prep stages concurrently.
//   blocks 0..255   : proj -> PX (32 yb rows each; W frags converted inline).
//   blocks 256..511 : ya -> yabf bf16 conversion.
//   block 511       : additionally zeroes svec.
// ---------------------------------------------------------------------------
__global__ __launch_bounds__(256) void k1_fused(
    const float* __restrict__ ya, const float* __restrict__ yb,
    const float* __restrict__ W, const float* __restrict__ bvec,
    unsigned short* __restrict__ yabf, unsigned short* __restrict__ PX,
    float* __restrict__ svec)
{
  const int b   = blockIdx.x;   // 0..511
  const int tid = threadIdx.x;

  if (b < 256) {
    // ---- proj part ----
    const int lane = tid & 63;
    const int w    = tid >> 6;   // st-quarter 0..3
    const int q    = lane >> 4;
    const int i    = lane & 15;

    frag_u B[2][8]; // 2 row-groups x 8 k-blocks of yb, bf16 B-frags
#pragma unroll
    for (int g = 0; g < 2; ++g) {
      const float* ybrow = yb + (size_t)(b * 32 + g * 16 + i) * HDIM;
#pragma unroll
      for (int kb = 0; kb < 8; ++kb) {
        float4 v0 = *(const float4*)&ybrow[kb * 32 + q * 8];
        float4 v1 = *(const float4*)&ybrow[kb * 32 + q * 8 + 4];
        B[g][kb].d[0] = f2bf2(v0.x, v0.y); B[g][kb].d[1] = f2bf2(v0.z, v0.w);
        B[g][kb].d[2] = f2bf2(v1.x, v1.y); B[g][kb].d[3] = f2bf2(v1.z, v1.w);
      }
    }

#pragma unroll
    for (int t = 0; t < 4; ++t) {
      const int st = w * 4 + t;
      f32x4 acc[2] = {{0.f,0.f,0.f,0.f},{0.f,0.f,0.f,0.f}};
#pragma unroll
      for (int kb = 0; kb < 8; ++kb) {
        const float* wr = W + (size_t)(st * 16 + i) * HDIM + kb * 32 + q * 8;
        float4 w0 = *(const float4*)wr;
        float4 w1 = *(const float4*)(wr + 4);
        frag_u Af;
        Af.d[0] = f2bf2(w0.x, w0.y); Af.d[1] = f2bf2(w0.z, w0.w);
        Af.d[2] = f2bf2(w1.x, w1.y); Af.d[3] = f2bf2(w1.z, w1.w);
#pragma unroll
        for (int g = 0; g < 2; ++g)
          acc[g] = __builtin_amdgcn_mfma_f32_16x16x32_bf16(Af.v, B[g][kb].v, acc[g], 0, 0, 0);
      }
      float4 bias = *(const float4*)&bvec[st * 16 + q * 4];
#pragma unroll
      for (int g = 0; g < 2; ++g) {
        const int jg = b * 2 + g;
        unsigned v0 = f2bf2(acc[g][0] + bias.x, acc[g][1] + bias.y);
        unsigned v1 = f2bf2(acc[g][2] + bias.z, acc[g][3] + bias.w);
        size_t off = (size_t)jg * 4096 + (size_t)(st >> 1) * 512
                   + (size_t)(((st & 1) << 1) | (q >> 1)) * 128 + i * 8 + ((q & 1) * 4);
        *(uint2*)(PX + off) = make_uint2(v0, v1);
      }
    }
  } else {
    // ---- ya -> bf16 conversion part (256 blocks, 262144 uint4 chunks) ----
    const int id = (b - 256) * 256 + tid;  // 0..65535
    const float4* src = (const float4*)ya;
    uint4* dst = (uint4*)yabf;
#pragma unroll
    for (int u = 0; u < 4; ++u) {
      int d = id + u * 65536;
      float4 a = src[d * 2];
      float4 c = src[d * 2 + 1];
      uint4 o = { f2bf2(a.x, a.y), f2bf2(a.z, a.w),
                  f2bf2(c.x, c.y), f2bf2(c.z, c.w) };
      dst[d] = o;
    }
    if (b == 511) {
      float4 z = {0.f, 0.f, 0.f, 0.f};
      float4* sv = (float4*)svec;
#pragma unroll
      for (int u = 0; u < 8; ++u) sv[u * 256 + tid] = z;
    }
  }
}

// ---------------------------------------------------------------------------
// k2: s[i] += sum_j sigmoid( ya[i] . proj[j] )
// OCCUPANCY version: grid 1024 (32 row-groups x 32 col-groups, 256x256 each),
// 2 x 16 KB LDS double buffer -> 4 blocks/CU (128 KB LDS), 4 waves/SIMD.
// Previous rounds proved the sync structure is NOT the bottleneck (3 variants
// within 2%); occupancy was pinned at 2 blocks/CU by the 512-block grid while
// both issue pipes sat ~30% busy -> latency-starved. Work per CU unchanged;
// wave parallelism doubles to hide the ds_read->MFMA and serial-sigmoid chains.
// Per tile: vmcnt(0) [near-free: loads had full compute phase in flight],
// s_barrier, stage t+1, compute (2 col16 phases, sigmoid pipelined accA/accB).
// ---------------------------------------------------------------------------
__global__ __launch_bounds__(256, 4) void k2_score(
    const unsigned short* __restrict__ yabf, const unsigned short* __restrict__ PX,
    float* __restrict__ svec)
{
  __shared__ __align__(16) unsigned short bs[2][8192]; // 2 x 16 KB
  const int tid  = threadIdx.x;
  const int lane = tid & 63;
  const int w    = tid >> 6;
  const int quad = lane >> 4;
  const int l15  = lane & 15;

  // XCD swizzle: bid = k*8 + xcd -> XCD 'xcd' sees only col-groups
  // {4xcd..4xcd+3} (512 KB of PX -> L2-resident per XCD).
  const int bid = blockIdx.x;           // 0..1023
  const int xcd = bid & 7;
  const int kk  = bid >> 3;             // 0..127
  const int by  = xcd * 4 + (kk >> 5);  // 0..31 col-group (256 cols)
  const int bx  = kk & 31;              // 0..31 row-group (256 rows)

  const int rbase = bx * 256 + w * 64;

  const unsigned short* psrc = PX + (size_t)by * 65536; // 16 col16-segs = 128 KB

#define STAGE(B, T)                                                          \
  do {                                                                       \
    const unsigned short* _src = psrc + (size_t)(T) * 8192;                  \
    unsigned short* _dst = &bs[(B)][0];                                      \
    _Pragma("unroll")                                                        \
    for (int p = 0; p < 4; ++p) {                                            \
      int c = p * 256 + tid;                                                 \
      __builtin_amdgcn_global_load_lds(                                      \
          (const __attribute__((address_space(1))) unsigned int*)(const void*)(_src + c * 8), \
          (__attribute__((address_space(3))) unsigned int*)(void*)(_dst + c * 8), \
          16, 0, 0);                                                         \
    }                                                                        \
  } while (0)

  // stage tile 0 first so its loads are oldest in the FIFO
  STAGE(0, 0);

  // A-frags: 64 ya rows per wave, direct bf16 16B loads (32 dwordx4/thread)
  frag_u A[4][8];
#pragma unroll
  for (int g = 0; g < 4; ++g) {
    const unsigned short* src = yabf + (size_t)(rbase + g * 16 + l15) * HDIM;
#pragma unroll
    for (int kb = 0; kb < 8; ++kb)
      A[g][kb].v = *(const bf16x8*)&src[kb * 32 + quad * 8];
  }

  float rs[4][4] = {{0.f,0.f,0.f,0.f},{0.f,0.f,0.f,0.f},
                    {0.f,0.f,0.f,0.f},{0.f,0.f,0.f,0.f}};

#define MFMA_PHASE(ACC, BUF, P)                                              \
  do {                                                                       \
    _Pragma("unroll")                                                        \
    for (int g = 0; g < 4; ++g) ACC[g] = (f32x4){0.f, 0.f, 0.f, 0.f};        \
    __builtin_amdgcn_s_setprio(1);                                           \
    _Pragma("unroll")                                                        \
    for (int kb = 0; kb < 8; ++kb) {                                         \
      bf16x8 bfrag = *(const bf16x8*)&BUF[(P) * 4096 + kb * 512 + lane * 8]; \
      _Pragma("unroll")                                                      \
      for (int g = 0; g < 4; ++g)                                            \
        ACC[g] = __builtin_amdgcn_mfma_f32_16x16x32_bf16(                    \
            A[g][kb].v, bfrag, ACC[g], 0, 0, 0);                             \
    }                                                                        \
    __builtin_amdgcn_s_setprio(0);                                           \
  } while (0)

#define SIG(ACC)                                                             \
  do {                                                                       \
    _Pragma("unroll")                                                        \
    for (int g = 0; g < 4; ++g)                                              \
      _Pragma("unroll")                                                      \
      for (int r = 0; r < 4; ++r)                                            \
        rs[g][r] += sigmoidf_fast(ACC[g][r]);                                \
  } while (0)

  for (int t = 0; t < 8; ++t) {        // 8 tiles x 32 cols = 256 cols
    asm volatile("s_waitcnt vmcnt(0)" ::: "memory"); // my tile-t loads done
    asm volatile("s_barrier" ::: "memory");          // everyone's tile-t loads done
    if (t < 7)
      STAGE((t + 1) & 1, t + 1);       // overlaps the whole compute phase below

    const unsigned short* buf = &bs[t & 1][0];
    f32x4 accA[4], accB[4];
    // sigmoid of phase A runs behind the MFMAs of phase B
    MFMA_PHASE(accA, buf, 0);
    MFMA_PHASE(accB, buf, 1);
    SIG(accA);
    SIG(accB);
  }
#undef STAGE
#undef MFMA_PHASE
#undef SIG

  // reduce over the 16 col-lanes within each quad group
#pragma unroll
  for (int off = 1; off < 16; off <<= 1)
#pragma unroll
    for (int g = 0; g < 4; ++g)
#pragma unroll
      for (int r = 0; r < 4; ++r)
        rs[g][r] += __shfl_xor(rs[g][r], off, 64);

  if (l15 == 0) {
#pragma unroll
    for (int g = 0; g < 4; ++g)
#pragma unroll
      for (int r = 0; r < 4; ++r)
        atomicAdd(&svec[rbase + g * 16 + quad * 4 + r], rs[g][r]);
  }
}

// ---------------------------------------------------------------------------
// k3: out[i][k] = s[i] / 256
// ---------------------------------------------------------------------------
__global__ __launch_bounds__(256) void k3_bcast(
    const float* __restrict__ svec, float* __restrict__ out)
{
  int idx = blockIdx.x * 256 + threadIdx.x;
  int row = idx >> 6;
  float v = svec[row] * (1.0f / 256.0f);
  float4 o = {v, v, v, v};
  ((float4*)out)[idx] = o;
}

extern "C" void kernel_launch(void* const* d_in, const int* in_sizes, int n_in,
                              void* d_out, int out_size, void* d_ws, size_t ws_size,
                              hipStream_t stream) {
  (void)in_sizes; (void)n_in; (void)out_size;
  const float* ya = (const float*)d_in[0];
  const float* yb = (const float*)d_in[1];
  const float* W  = (const float*)d_in[2];
  const float* bv = (const float*)d_in[3];
  float* out = (float*)d_out;

  char* ws = (char*)d_ws;
  unsigned short *PX, *yabf;
  float* svec;
  const size_t need = (8ull << 20) + (32ull << 10);
  if (ws_size >= need) {
    PX   = (unsigned short*)ws;
    yabf = (unsigned short*)(ws + (4 << 20));
    svec = (float*)(ws + (8 << 20));
  } else {
    PX   = (unsigned short*)d_out;                 // aliases out; k3 rewrites all
    yabf = (unsigned short*)((char*)d_out + (4 << 20));
    svec = (float*)ws;
  }

  k1_fused<<<512, 256, 0, stream>>>(ya, yb, W, bv, yabf, PX, svec);
  k2_score<<<1024, 256, 0, stream>>>(yabf, PX, svec);
  k3_bcast<<<2048, 256, 0, stream>>>(svec, out);
}

// Round 6
// 121.563 us; speedup vs baseline: 2.1290x; 2.1290x over previous
//
#include <hip/hip_runtime.h>

#define NUSR 8192
#define HDIM 256

typedef __attribute__((ext_vector_type(8))) __bf16 bf16x8;
typedef __attribute__((ext_vector_type(4))) float f32x4;

union frag_u { bf16x8 v; unsigned short u[8]; unsigned int d[4]; };

// f32 -> bf16 RNE
__device__ __forceinline__ unsigned int f2bf(float f) {
  unsigned u = __builtin_bit_cast(unsigned, f);
  u += 0x7FFFu + ((u >> 16) & 1u);
  return u >> 16;
}
__device__ __forceinline__ unsigned int f2bf2(float lo, float hi) {
  return f2bf(lo) | (f2bf(hi) << 16);
}
__device__ __forceinline__ float sigmoidf_fast(float x) {
  float e = __builtin_amdgcn_exp2f(x * -1.44269504088896340736f);
  return __builtin_amdgcn_rcpf(1.0f + e);
}

// PX layout (proj in MFMA-B fragment order), ushort offsets:
//   PX[(col>>4)*4096 + (k>>5)*512 + ((k>>3)&3)*128 + (col&15)*8 + (k&7)]
// -> B-frag for (col16 ct, kb) = 16B at PX + ct*4096 + kb*512 + lane*8 (lane-linear).

// ---------------------------------------------------------------------------
// k1_fused: ONE launch doing both prep stages concurrently.
//   blocks 0..255   : proj -> PX (32 yb rows each; W frags converted inline).
//   blocks 256..511 : ya -> yabf bf16 conversion.
//   block 511       : additionally zeroes svec.
// ---------------------------------------------------------------------------
__global__ __launch_bounds__(256) void k1_fused(
    const float* __restrict__ ya, const float* __restrict__ yb,
    const float* __restrict__ W, const float* __restrict__ bvec,
    unsigned short* __restrict__ yabf, unsigned short* __restrict__ PX,
    float* __restrict__ svec)
{
  const int b   = blockIdx.x;   // 0..511
  const int tid = threadIdx.x;

  if (b < 256) {
    // ---- proj part ----
    const int lane = tid & 63;
    const int w    = tid >> 6;   // st-quarter 0..3
    const int q    = lane >> 4;
    const int i    = lane & 15;

    frag_u B[2][8]; // 2 row-groups x 8 k-blocks of yb, bf16 B-frags
#pragma unroll
    for (int g = 0; g < 2; ++g) {
      const float* ybrow = yb + (size_t)(b * 32 + g * 16 + i) * HDIM;
#pragma unroll
      for (int kb = 0; kb < 8; ++kb) {
        float4 v0 = *(const float4*)&ybrow[kb * 32 + q * 8];
        float4 v1 = *(const float4*)&ybrow[kb * 32 + q * 8 + 4];
        B[g][kb].d[0] = f2bf2(v0.x, v0.y); B[g][kb].d[1] = f2bf2(v0.z, v0.w);
        B[g][kb].d[2] = f2bf2(v1.x, v1.y); B[g][kb].d[3] = f2bf2(v1.z, v1.w);
      }
    }

#pragma unroll
    for (int t = 0; t < 4; ++t) {
      const int st = w * 4 + t;
      f32x4 acc[2] = {{0.f,0.f,0.f,0.f},{0.f,0.f,0.f,0.f}};
#pragma unroll
      for (int kb = 0; kb < 8; ++kb) {
        const float* wr = W + (size_t)(st * 16 + i) * HDIM + kb * 32 + q * 8;
        float4 w0 = *(const float4*)wr;
        float4 w1 = *(const float4*)(wr + 4);
        frag_u Af;
        Af.d[0] = f2bf2(w0.x, w0.y); Af.d[1] = f2bf2(w0.z, w0.w);
        Af.d[2] = f2bf2(w1.x, w1.y); Af.d[3] = f2bf2(w1.z, w1.w);
#pragma unroll
        for (int g = 0; g < 2; ++g)
          acc[g] = __builtin_amdgcn_mfma_f32_16x16x32_bf16(Af.v, B[g][kb].v, acc[g], 0, 0, 0);
      }
      float4 bias = *(const float4*)&bvec[st * 16 + q * 4];
#pragma unroll
      for (int g = 0; g < 2; ++g) {
        const int jg = b * 2 + g;
        unsigned v0 = f2bf2(acc[g][0] + bias.x, acc[g][1] + bias.y);
        unsigned v1 = f2bf2(acc[g][2] + bias.z, acc[g][3] + bias.w);
        size_t off = (size_t)jg * 4096 + (size_t)(st >> 1) * 512
                   + (size_t)(((st & 1) << 1) | (q >> 1)) * 128 + i * 8 + ((q & 1) * 4);
        *(uint2*)(PX + off) = make_uint2(v0, v1);
      }
    }
  } else {
    // ---- ya -> bf16 conversion part (256 blocks, 262144 uint4 chunks) ----
    const int id = (b - 256) * 256 + tid;  // 0..65535
    const float4* src = (const float4*)ya;
    uint4* dst = (uint4*)yabf;
#pragma unroll
    for (int u = 0; u < 4; ++u) {
      int d = id + u * 65536;
      float4 a = src[d * 2];
      float4 c = src[d * 2 + 1];
      uint4 o = { f2bf2(a.x, a.y), f2bf2(a.z, a.w),
                  f2bf2(c.x, c.y), f2bf2(c.z, c.w) };
      dst[d] = o;
    }
    if (b == 511) {
      float4 z = {0.f, 0.f, 0.f, 0.f};
      float4* sv = (float4*)svec;
#pragma unroll
      for (int u = 0; u < 8; ++u) sv[u * 256 + tid] = z;
    }
  }
}

// ---------------------------------------------------------------------------
// k2: s[i] += sum_j sigmoid( ya[i] . proj[j] )
// TRUE-A-RESIDENCY version. Root cause found in r5: with VGPR caps <= 128 the
// compiler REMATERIALIZES the 32 A-frag global loads inside the tile loop
// (rounds 0-4: VGPR=104-112 < the 128 A needs; ~1 GB/kernel of L2 A-traffic
// -> the invariant 46 us). Fix: load A once and make it opaque via
// asm volatile("" : "+v") so remat is impossible; launch_bounds(256,2) gives
// the 256-VGPR budget (~210 used). Grid 512 (2 blocks/CU), 2 x 32 KB LDS
// double buffer, 64-col tiles, counted-sync structure proven race-free in r4.
// ---------------------------------------------------------------------------
__global__ __launch_bounds__(256, 2) void k2_score(
    const unsigned short* __restrict__ yabf, const unsigned short* __restrict__ PX,
    float* __restrict__ svec)
{
  __shared__ __align__(16) unsigned short bs[2][16384]; // 2 x 32 KB
  const int tid  = threadIdx.x;
  const int lane = tid & 63;
  const int w    = tid >> 6;
  const int quad = lane >> 4;
  const int l15  = lane & 15;

  // XCD swizzle: bid = k*8 + xcd -> XCD 'xcd' sees only col-slices {2xcd, 2xcd+1}
  const int bid = blockIdx.x;          // 0..511
  const int xcd = bid & 7;
  const int k   = bid >> 3;            // 0..63
  const int by  = xcd * 2 + (k >> 5);  // 0..15
  const int bx  = k & 31;              // 0..31

  const int rbase = bx * 256 + w * 64;
  const int cg16  = by * 32;           // col16-group base (512 cols)

  const unsigned short* psrc = PX + (size_t)cg16 * 4096; // this block's 256 KB

#define STAGE(B, T)                                                          \
  do {                                                                       \
    const unsigned short* _src = psrc + (size_t)(T) * 16384;                 \
    unsigned short* _dst = &bs[(B)][0];                                      \
    _Pragma("unroll")                                                        \
    for (int p = 0; p < 8; ++p) {                                            \
      int c = p * 256 + tid;                                                 \
      __builtin_amdgcn_global_load_lds(                                      \
          (const __attribute__((address_space(1))) unsigned int*)(const void*)(_src + c * 8), \
          (__attribute__((address_space(3))) unsigned int*)(void*)(_dst + c * 8), \
          16, 0, 0);                                                         \
    }                                                                        \
  } while (0)

  // stage tile 0 first so its loads are oldest in the FIFO
  STAGE(0, 0);

  // A-frags: 64 ya rows per wave. Loaded ONCE; the empty asm makes each value
  // opaque so the compiler cannot re-load it inside the loop (r5 post-mortem).
  frag_u A[4][8];
#pragma unroll
  for (int g = 0; g < 4; ++g) {
    const unsigned short* src = yabf + (size_t)(rbase + g * 16 + l15) * HDIM;
#pragma unroll
    for (int kb = 0; kb < 8; ++kb)
      A[g][kb].v = *(const bf16x8*)&src[kb * 32 + quad * 8];
  }
#pragma unroll
  for (int g = 0; g < 4; ++g)
#pragma unroll
    for (int kb = 0; kb < 8; ++kb)
      asm volatile("" : "+v"(A[g][kb].v));   // pin in VGPRs; forbid remat

  float rs[4][4] = {{0.f,0.f,0.f,0.f},{0.f,0.f,0.f,0.f},
                    {0.f,0.f,0.f,0.f},{0.f,0.f,0.f,0.f}};

#define MFMA_PHASE(ACC, BUF, P)                                              \
  do {                                                                       \
    _Pragma("unroll")                                                        \
    for (int g = 0; g < 4; ++g) ACC[g] = (f32x4){0.f, 0.f, 0.f, 0.f};        \
    __builtin_amdgcn_s_setprio(1);                                           \
    _Pragma("unroll")                                                        \
    for (int kb = 0; kb < 8; ++kb) {                                         \
      bf16x8 bfrag = *(const bf16x8*)&BUF[(P) * 4096 + kb * 512 + lane * 8]; \
      _Pragma("unroll")                                                      \
      for (int g = 0; g < 4; ++g)                                            \
        ACC[g] = __builtin_amdgcn_mfma_f32_16x16x32_bf16(                    \
            A[g][kb].v, bfrag, ACC[g], 0, 0, 0);                             \
    }                                                                        \
    __builtin_amdgcn_s_setprio(0);                                           \
  } while (0)

#define SIG(ACC)                                                             \
  do {                                                                       \
    _Pragma("unroll")                                                        \
    for (int g = 0; g < 4; ++g)                                              \
      _Pragma("unroll")                                                      \
      for (int r = 0; r < 4; ++r)                                            \
        rs[g][r] += sigmoidf_fast(ACC[g][r]);                                \
  } while (0)

  for (int t = 0; t < 8; ++t) {        // 8 tiles x 64 cols = 512 cols
    asm volatile("s_waitcnt vmcnt(0)" ::: "memory"); // my tile-t loads done (near-free)
    asm volatile("s_barrier" ::: "memory");          // everyone's tile-t loads done
    if (t < 7)
      STAGE((t + 1) & 1, t + 1);       // overlaps the whole compute phase below

    const unsigned short* buf = &bs[t & 1][0];
    f32x4 accA[4], accB[4];
    // software-pipelined: sigmoid of phase p-1 runs behind MFMAs of phase p
    MFMA_PHASE(accA, buf, 0);
    MFMA_PHASE(accB, buf, 1);
    SIG(accA);
    MFMA_PHASE(accA, buf, 2);
    SIG(accB);
    MFMA_PHASE(accB, buf, 3);
    SIG(accA);
    SIG(accB);
  }
#undef STAGE
#undef MFMA_PHASE
#undef SIG

  // reduce over the 16 col-lanes within each quad group
#pragma unroll
  for (int off = 1; off < 16; off <<= 1)
#pragma unroll
    for (int g = 0; g < 4; ++g)
#pragma unroll
      for (int r = 0; r < 4; ++r)
        rs[g][r] += __shfl_xor(rs[g][r], off, 64);

  if (l15 == 0) {
#pragma unroll
    for (int g = 0; g < 4; ++g)
#pragma unroll
      for (int r = 0; r < 4; ++r)
        atomicAdd(&svec[rbase + g * 16 + quad * 4 + r], rs[g][r]);
  }
}

// ---------------------------------------------------------------------------
// k3: out[i][k] = s[i] / 256
// ---------------------------------------------------------------------------
__global__ __launch_bounds__(256) void k3_bcast(
    const float* __restrict__ svec, float* __restrict__ out)
{
  int idx = blockIdx.x * 256 + threadIdx.x;
  int row = idx >> 6;
  float v = svec[row] * (1.0f / 256.0f);
  float4 o = {v, v, v, v};
  ((float4*)out)[idx] = o;
}

extern "C" void kernel_launch(void* const* d_in, const int* in_sizes, int n_in,
                              void* d_out, int out_size, void* d_ws, size_t ws_size,
                              hipStream_t stream) {
  (void)in_sizes; (void)n_in; (void)out_size;
  const float* ya = (const float*)d_in[0];
  const float* yb = (const float*)d_in[1];
  const float* W  = (const float*)d_in[2];
  const float* bv = (const float*)d_in[3];
  float* out = (float*)d_out;

  char* ws = (char*)d_ws;
  unsigned short *PX, *yabf;
  float* svec;
  const size_t need = (8ull << 20) + (32ull << 10);
  if (ws_size >= need) {
    PX   = (unsigned short*)ws;
    yabf = (unsigned short*)(ws + (4 << 20));
    svec = (float*)(ws + (8 << 20));
  } else {
    PX   = (unsigned short*)d_out;                 // aliases out; k3 rewrites all
    yabf = (unsigned short*)((char*)d_out + (4 << 20));
    svec = (float*)ws;
  }

  k1_fused<<<512, 256, 0, stream>>>(ya, yb, W, bv, yabf, PX, svec);
  k2_score<<<512, 256, 0, stream>>>(yabf, PX, svec);
  k3_bcast<<<2048, 256, 0, stream>>>(svec, out);
}